// Round 2
// baseline (4356.647 us; speedup 1.0000x reference)
//
#include <hip/hip_runtime.h>
#include <hip/hip_bf16.h>

#define N_NODES 100000
#define N_EDGES 1000000
#define N_GRAPHS 2048
#define F_IN 128
#define HC 64
#define NEG_SLOPE 0.2f

// order-preserving float->uint encoding for atomicMax on signed floats
__device__ __forceinline__ unsigned fenc(float x) {
    unsigned u = __float_as_uint(x);
    return (u & 0x80000000u) ? ~u : (u | 0x80000000u);
}
__device__ __forceinline__ float fdec(unsigned k) {
    unsigned u = (k & 0x80000000u) ? (k ^ 0x80000000u) : ~k;
    return __uint_as_float(u);
}

// ---------------- K1: xlr = x @ [W_l | W_r]  (f32 out, [N][128]) --------------
__global__ __launch_bounds__(256) void k_gemm(const float* __restrict__ x,
                                              const float* __restrict__ Wl,
                                              const float* __restrict__ Wr,
                                              float* __restrict__ xlr) {
    __shared__ float xs[2][F_IN];
    int tid = threadIdx.x;
    int rl = tid >> 7;           // 0..1 local row
    int col = tid & 127;         // 0..127 output column (also k for staging)
    int r = blockIdx.x * 2 + rl;
    xs[rl][col] = (r < N_NODES) ? x[(size_t)r * F_IN + col] : 0.f;
    __syncthreads();
    if (r >= N_NODES) return;
    const float* W = (col < 64) ? (Wl + col) : (Wr + (col - 64));
    float acc = 0.f;
#pragma unroll 8
    for (int k = 0; k < F_IN; ++k)
        acc += xs[rl][k] * W[(size_t)k * 64];
    xlr[(size_t)r * 128 + col] = acc;
}

// ---------------- K2: per-(edge,head) logits + per-(dst,head) max ------------
__global__ __launch_bounds__(256) void k_logits(const int* __restrict__ ei,
                                                const float* __restrict__ xlr,
                                                const float* __restrict__ att,
                                                float* __restrict__ logits,
                                                unsigned* __restrict__ mkey) {
    int idx = blockIdx.x * 256 + threadIdx.x;
    const int tot = (N_EDGES + N_NODES) * 2;
    if (idx >= tot) return;
    int e = idx >> 1, h = idx & 1;
    int s, d;
    if (e < N_EDGES) { s = ei[e]; d = ei[N_EDGES + e]; }
    else             { s = d = e - N_EDGES; }
    const float* pl = xlr + (size_t)s * 128 + h * 32;        // xl[s], head h
    const float* pr = xlr + (size_t)d * 128 + 64 + h * 32;   // xr[d], head h
    float acc = 0.f;
#pragma unroll
    for (int c = 0; c < 32; ++c) {
        float v = pl[c] + pr[c];
        v = (v > 0.f) ? v : NEG_SLOPE * v;
        acc += v * att[h * 32 + c];
    }
    logits[idx] = acc;
    atomicMax(&mkey[d * 2 + h], fenc(acc));
}

// ---------------- K3: accumulate exp-weighted features + denom ----------------
__global__ __launch_bounds__(256) void k_accum(const int* __restrict__ ei,
                                               const float* __restrict__ xlr,
                                               const float* __restrict__ logits,
                                               const unsigned* __restrict__ mkey,
                                               float* __restrict__ denom,
                                               float* __restrict__ hnum) {
    int idx = blockIdx.x * 256 + threadIdx.x;
    const int tot = (N_EDGES + N_NODES) * 2;
    if (idx >= tot) return;
    int e = idx >> 1, h = idx & 1;
    int s, d;
    if (e < N_EDGES) { s = ei[e]; d = ei[N_EDGES + e]; }
    else             { s = d = e - N_EDGES; }
    float m = fdec(mkey[d * 2 + h]);
    float w = __expf(logits[idx] - m);
    atomicAdd(&denom[d * 2 + h], w);
    const float* pl = xlr + (size_t)s * 128 + h * 32;
    float* pd = hnum + (size_t)d * 64 + h * 32;
#pragma unroll
    for (int c = 0; c < 32; ++c)
        atomicAdd(&pd[c], w * pl[c]);
}

// ---------------- K4: h = hnum/denom + bias ----------------------------------
__global__ __launch_bounds__(256) void k_norm(float* __restrict__ hnum,
                                              const float* __restrict__ denom,
                                              const float* __restrict__ bias) {
    int idx = blockIdx.x * 256 + threadIdx.x;
    if (idx >= N_NODES * 64) return;
    int i = idx >> 6, c = idx & 63;
    hnum[idx] = hnum[idx] / denom[i * 2 + (c >> 5)] + bias[c];
}

// ---------------- K5: per-node dots t = h.w_rel, r = h.w_root ----------------
__global__ __launch_bounds__(256) void k_tr(const float* __restrict__ h,
                                            const float* __restrict__ w_rel,
                                            const float* __restrict__ w_root,
                                            float* __restrict__ t, float* __restrict__ r) {
    int i = blockIdx.x * 256 + threadIdx.x;
    if (i >= N_NODES) return;
    const float* hp = h + (size_t)i * 64;
    float a = 0.f, b = 0.f;
#pragma unroll
    for (int c = 0; c < 64; ++c) {
        float v = hp[c];
        a += v * w_rel[c];
        b += v * w_root[c];
    }
    t[i] = a; r[i] = b;
}

// ---------------- K6: score[dst] += t[src] over original edges ---------------
__global__ __launch_bounds__(256) void k_escore(const int* __restrict__ ei,
                                                const float* __restrict__ t,
                                                float* __restrict__ score) {
    int e = blockIdx.x * 256 + threadIdx.x;
    if (e >= N_EDGES) return;
    atomicAdd(&score[ei[N_EDGES + e]], t[ei[e]]);
}

// ---------------- K7: score += r + b_score -----------------------------------
__global__ __launch_bounds__(256) void k_sfin(float* __restrict__ score,
                                              const float* __restrict__ r,
                                              const float* __restrict__ b_score) {
    int i = blockIdx.x * 256 + threadIdx.x;
    if (i >= N_NODES) return;
    score[i] += r[i] + b_score[0];
}

// ---------------- K8: graph start offsets from sorted batch ------------------
__global__ __launch_bounds__(256) void k_bounds(const int* __restrict__ batch,
                                                int* __restrict__ start) {
    int i = blockIdx.x * 256 + threadIdx.x;
    if (i >= N_NODES) return;
    int bi = batch[i];
    int bp = (i == 0) ? -1 : batch[i - 1];
    for (int g = bp + 1; g <= bi; ++g) start[g] = i;
    if (i == N_NODES - 1)
        for (int g = bi + 1; g <= N_GRAPHS; ++g) start[g] = N_NODES;
}

// ---------------- K9: per-graph softmax-pool, out = add*(1+1/cnt) ------------
__global__ __launch_bounds__(64) void k_pool(const float* __restrict__ score,
                                             const float* __restrict__ h,
                                             const int* __restrict__ start,
                                             float* __restrict__ out) {
    int g = blockIdx.x;
    int lane = threadIdx.x;             // 64 threads = 1 wave = 64 channels
    int n0 = start[g], n1 = start[g + 1];
    int cnt = n1 - n0;
    if (cnt <= 0) { out[(size_t)g * 64 + lane] = 0.f; return; }
    float m = -1e30f;
    for (int i = n0 + lane; i < n1; i += 64) m = fmaxf(m, score[i]);
#pragma unroll
    for (int o = 32; o; o >>= 1) m = fmaxf(m, __shfl_xor(m, o, 64));
    float ssum = 0.f;
    for (int i = n0 + lane; i < n1; i += 64) ssum += __expf(score[i] - m);
#pragma unroll
    for (int o = 32; o; o >>= 1) ssum += __shfl_xor(ssum, o, 64);
    float acc = 0.f;
    for (int i = n0; i < n1; ++i)
        acc += __expf(score[i] - m) * h[(size_t)i * 64 + lane];
    float coeff = (1.f + 1.f / (float)cnt) / ssum;
    out[(size_t)g * 64 + lane] = acc * coeff;
}

extern "C" void kernel_launch(void* const* d_in, const int* in_sizes, int n_in,
                              void* d_out, int out_size, void* d_ws, size_t ws_size,
                              hipStream_t stream) {
    const float* x      = (const float*)d_in[0];
    const int*   ei     = (const int*)d_in[1];
    const int*   batch  = (const int*)d_in[2];
    const float* Wl     = (const float*)d_in[3];
    const float* Wr     = (const float*)d_in[4];
    const float* att    = (const float*)d_in[5];
    const float* bias   = (const float*)d_in[6];
    const float* w_rel  = (const float*)d_in[7];
    const float* w_root = (const float*)d_in[8];
    const float* b_sc   = (const float*)d_in[9];

    char* ws = (char*)d_ws;
    size_t off = 0;
    auto alloc = [&](size_t bytes) { void* p = ws + off; off += (bytes + 255) & ~255ull; return p; };
    float*    xlr    = (float*)   alloc((size_t)N_NODES * 128 * 4);          // 51.2 MB
    float*    logits = (float*)   alloc((size_t)(N_EDGES + N_NODES) * 2 * 4);// 8.8 MB
    unsigned* mkey   = (unsigned*)alloc((size_t)N_NODES * 2 * 4);
    float*    denom  = (float*)   alloc((size_t)N_NODES * 2 * 4);
    float*    hfeat  = (float*)   alloc((size_t)N_NODES * 64 * 4);           // 25.6 MB
    float*    tbuf   = (float*)   alloc((size_t)N_NODES * 4);
    float*    rbuf   = (float*)   alloc((size_t)N_NODES * 4);
    float*    score  = (float*)   alloc((size_t)N_NODES * 4);
    int*      start  = (int*)     alloc((size_t)(N_GRAPHS + 1) * 4);

    hipMemsetAsync(mkey,  0, (size_t)N_NODES * 2 * 4, stream);   // enc(-inf)=0
    hipMemsetAsync(denom, 0, (size_t)N_NODES * 2 * 4, stream);
    hipMemsetAsync(hfeat, 0, (size_t)N_NODES * 64 * 4, stream);
    hipMemsetAsync(score, 0, (size_t)N_NODES * 4, stream);

    k_gemm<<<(N_NODES + 1) / 2, 256, 0, stream>>>(x, Wl, Wr, xlr);
    const int tot = (N_EDGES + N_NODES) * 2;
    k_logits<<<(tot + 255) / 256, 256, 0, stream>>>(ei, xlr, att, logits, mkey);
    k_accum <<<(tot + 255) / 256, 256, 0, stream>>>(ei, xlr, logits, mkey, denom, hfeat);
    k_norm  <<<(N_NODES * 64 + 255) / 256, 256, 0, stream>>>(hfeat, denom, bias);
    k_tr    <<<(N_NODES + 255) / 256, 256, 0, stream>>>(hfeat, w_rel, w_root, tbuf, rbuf);
    k_escore<<<(N_EDGES + 255) / 256, 256, 0, stream>>>(ei, tbuf, score);
    k_sfin  <<<(N_NODES + 255) / 256, 256, 0, stream>>>(score, rbuf, b_sc);
    k_bounds<<<(N_NODES + 255) / 256, 256, 0, stream>>>(batch, start);
    k_pool  <<<N_GRAPHS, 64, 0, stream>>>(score, hfeat, start, (float*)d_out);
}

// Round 3
// 457.362 us; speedup vs baseline: 9.5256x; 9.5256x over previous
//
#include <hip/hip_runtime.h>
#include <hip/hip_bf16.h>

#define N_NODES 100000
#define N_EDGES 1000000
#define N_GRAPHS 2048
#define F_IN 128
#define HC 64
#define NEG_SLOPE 0.2f
#define E_TOT (N_EDGES + N_NODES)   // edges + self-loops
#define SCAN_BLK 98                 // ceil(100000/1024)

// ---------------- K1: xlr = x @ [W_l | W_r]  (f32 out, [N][128]) --------------
// 16 rows per block; W re-read once per 16 rows (0.8 GB total, L2-resident).
__global__ __launch_bounds__(256) void k_gemm(const float* __restrict__ x,
                                              const float* __restrict__ Wl,
                                              const float* __restrict__ Wr,
                                              float* __restrict__ xlr) {
    __shared__ float xs[16][F_IN];
    int tid = threadIdx.x;
    int row0 = blockIdx.x * 16;                  // N_NODES % 16 == 0, no guards
    // stage 16x128 floats = 512 float4, 2 per thread
    const float4* xv = (const float4*)(x + (size_t)row0 * F_IN);
#pragma unroll
    for (int i = 0; i < 2; ++i) {
        int li = tid + i * 256;                  // float4 index within tile
        ((float4*)xs)[li] = xv[li];
    }
    __syncthreads();
    int col = tid & 127;
    int rl0 = tid >> 7;                          // 0..1
    const float* W = (col < 64) ? (Wl + col) : (Wr + (col - 64));
    float acc[8] = {0.f, 0.f, 0.f, 0.f, 0.f, 0.f, 0.f, 0.f};
    for (int k = 0; k < F_IN; ++k) {
        float wv = W[(size_t)k * 64];
#pragma unroll
        for (int j = 0; j < 8; ++j)
            acc[j] += xs[rl0 + j * 2][k] * wv;
    }
#pragma unroll
    for (int j = 0; j < 8; ++j)
        xlr[(size_t)(row0 + rl0 + j * 2) * 128 + col] = acc[j];
}

// ---------------- K2: histogram of destinations (incl. self-loops) ------------
__global__ __launch_bounds__(256) void k_hist(const int* __restrict__ ei,
                                              int* __restrict__ counts) {
    int e = blockIdx.x * 256 + threadIdx.x;
    if (e >= E_TOT) return;
    int d = (e < N_EDGES) ? ei[N_EDGES + e] : (e - N_EDGES);
    atomicAdd(&counts[d], 1);
}

// ---------------- K3a/b/c: exclusive scan -> rowptr, cursor ------------------
__global__ __launch_bounds__(256) void k_scanA(const int* __restrict__ counts,
                                               int* __restrict__ rowptr,
                                               int* __restrict__ bsum) {
    __shared__ int sh[256];
    int t = threadIdx.x, b = blockIdx.x;
    int base = b * 1024 + t * 4;
    int v[4]; int s = 0;
#pragma unroll
    for (int i = 0; i < 4; ++i) {
        int idx = base + i;
        v[i] = (idx < N_NODES) ? counts[idx] : 0;
        s += v[i];
    }
    sh[t] = s; __syncthreads();
    for (int off = 1; off < 256; off <<= 1) {
        int xv = (t >= off) ? sh[t - off] : 0;
        __syncthreads();
        sh[t] += xv;
        __syncthreads();
    }
    int run = sh[t] - s;                         // exclusive prefix in block
    if (t == 255) bsum[b] = sh[255];
#pragma unroll
    for (int i = 0; i < 4; ++i) {
        int idx = base + i;
        if (idx < N_NODES) rowptr[idx] = run;
        run += v[i];
    }
}

__global__ void k_scanB(int* __restrict__ bsum, int* __restrict__ rowptr) {
    if (threadIdx.x == 0) {
        int run = 0;
        for (int i = 0; i < SCAN_BLK; ++i) { int xv = bsum[i]; bsum[i] = run; run += xv; }
        rowptr[N_NODES] = run;                   // == E_TOT
    }
}

__global__ __launch_bounds__(256) void k_scanC(int* __restrict__ rowptr,
                                               const int* __restrict__ bsum,
                                               int* __restrict__ cursor) {
    int i = blockIdx.x * 256 + threadIdx.x;
    if (i >= N_NODES) return;
    int v = rowptr[i] + bsum[i >> 10];
    rowptr[i] = v;
    cursor[i] = v;
}

// ---------------- K4: scatter edges into dst-sorted order --------------------
__global__ __launch_bounds__(256) void k_scatter(const int* __restrict__ ei,
                                                 int* __restrict__ cursor,
                                                 int* __restrict__ sorted_src) {
    int e = blockIdx.x * 256 + threadIdx.x;
    if (e >= E_TOT) return;
    int s, d;
    if (e < N_EDGES) { s = ei[e]; d = ei[N_EDGES + e]; }
    else             { s = d = e - N_EDGES; }
    int pos = atomicAdd(&cursor[d], 1);
    sorted_src[pos] = s;
}

// ---------------- K5: fused GATv2 per dst node (online softmax) --------------
// one wave per dst; lane = h*32+c output channel. Also emits t,r dots.
__global__ __launch_bounds__(256) void k_gat(const float* __restrict__ xlr,
                                             const int* __restrict__ rowptr,
                                             const int* __restrict__ sorted_src,
                                             const float* __restrict__ att,
                                             const float* __restrict__ bias,
                                             const float* __restrict__ w_rel,
                                             const float* __restrict__ w_root,
                                             float* __restrict__ hfeat,
                                             float* __restrict__ tbuf,
                                             float* __restrict__ rbuf) {
    int d = blockIdx.x * 4 + (threadIdx.x >> 6);
    if (d >= N_NODES) return;
    int lane = threadIdx.x & 63;
    float xr_l  = xlr[(size_t)d * 128 + 64 + lane];   // xr[d], channel lane
    float att_l = att[lane];
    int j0 = rowptr[d], j1 = rowptr[d + 1];
    float m = -1e30f, wsum = 0.f, acc = 0.f;
    for (int j = j0; j < j1; ++j) {
        int s = sorted_src[j];
        float xls = xlr[(size_t)s * 128 + lane];      // xl[s], channel lane
        float v = xls + xr_l;
        v = (v > 0.f) ? v : NEG_SLOPE * v;
        float p = v * att_l;
#pragma unroll
        for (int o = 1; o < 32; o <<= 1) p += __shfl_xor(p, o, 64);  // per-head sum
        // p == logit for this lane's head, replicated across its 32 lanes
        if (p > m) {
            float sc = __expf(m - p);
            acc *= sc; wsum *= sc; m = p;
        }
        float w = __expf(p - m);
        wsum += w;
        acc += w * xls;
    }
    float h = acc / wsum + bias[lane];
    hfeat[(size_t)d * 64 + lane] = h;
    float a = h * w_rel[lane];
    float b = h * w_root[lane];
#pragma unroll
    for (int o = 1; o < 64; o <<= 1) { a += __shfl_xor(a, o, 64); b += __shfl_xor(b, o, 64); }
    if (lane == 0) { tbuf[d] = a; rbuf[d] = b; }
}

// ---------------- K6: score via sorted CSR (minus self-loop term) ------------
__global__ __launch_bounds__(256) void k_score(const int* __restrict__ rowptr,
                                               const int* __restrict__ sorted_src,
                                               const float* __restrict__ t,
                                               const float* __restrict__ r,
                                               const float* __restrict__ b_score,
                                               float* __restrict__ score) {
    int d = blockIdx.x * 256 + threadIdx.x;
    if (d >= N_NODES) return;
    int j0 = rowptr[d], j1 = rowptr[d + 1];
    float sum = 0.f;
    for (int j = j0; j < j1; ++j) sum += t[sorted_src[j]];
    // sorted list includes the appended self-loop exactly once -> subtract t[d]
    score[d] = sum - t[d] + r[d] + b_score[0];
}

// ---------------- K7: graph start offsets from sorted batch ------------------
__global__ __launch_bounds__(256) void k_bounds(const int* __restrict__ batch,
                                                int* __restrict__ start) {
    int i = blockIdx.x * 256 + threadIdx.x;
    if (i >= N_NODES) return;
    int bi = batch[i];
    int bp = (i == 0) ? -1 : batch[i - 1];
    for (int g = bp + 1; g <= bi; ++g) start[g] = i;
    if (i == N_NODES - 1)
        for (int g = bi + 1; g <= N_GRAPHS; ++g) start[g] = N_NODES;
}

// ---------------- K8: per-graph softmax-pool, out = add*(1+1/cnt) ------------
__global__ __launch_bounds__(64) void k_pool(const float* __restrict__ score,
                                             const float* __restrict__ h,
                                             const int* __restrict__ start,
                                             float* __restrict__ out) {
    int g = blockIdx.x;
    int lane = threadIdx.x;
    int n0 = start[g], n1 = start[g + 1];
    int cnt = n1 - n0;
    if (cnt <= 0) { out[(size_t)g * 64 + lane] = 0.f; return; }
    float m = -1e30f;
    for (int i = n0 + lane; i < n1; i += 64) m = fmaxf(m, score[i]);
#pragma unroll
    for (int o = 32; o; o >>= 1) m = fmaxf(m, __shfl_xor(m, o, 64));
    float ssum = 0.f;
    for (int i = n0 + lane; i < n1; i += 64) ssum += __expf(score[i] - m);
#pragma unroll
    for (int o = 32; o; o >>= 1) ssum += __shfl_xor(ssum, o, 64);
    float acc = 0.f;
    for (int i = n0; i < n1; ++i)
        acc += __expf(score[i] - m) * h[(size_t)i * 64 + lane];
    float coeff = (1.f + 1.f / (float)cnt) / ssum;
    out[(size_t)g * 64 + lane] = acc * coeff;
}

extern "C" void kernel_launch(void* const* d_in, const int* in_sizes, int n_in,
                              void* d_out, int out_size, void* d_ws, size_t ws_size,
                              hipStream_t stream) {
    const float* x      = (const float*)d_in[0];
    const int*   ei     = (const int*)d_in[1];
    const int*   batch  = (const int*)d_in[2];
    const float* Wl     = (const float*)d_in[3];
    const float* Wr     = (const float*)d_in[4];
    const float* att    = (const float*)d_in[5];
    const float* bias   = (const float*)d_in[6];
    const float* w_rel  = (const float*)d_in[7];
    const float* w_root = (const float*)d_in[8];
    const float* b_sc   = (const float*)d_in[9];

    char* ws = (char*)d_ws;
    size_t off = 0;
    auto alloc = [&](size_t bytes) { void* p = ws + off; off += (bytes + 255) & ~255ull; return p; };
    float* xlr        = (float*)alloc((size_t)N_NODES * 128 * 4);   // 51.2 MB
    float* hfeat      = (float*)alloc((size_t)N_NODES * 64 * 4);    // 25.6 MB
    int*   sorted_src = (int*)  alloc((size_t)E_TOT * 4);           // 4.4 MB
    int*   counts     = (int*)  alloc((size_t)N_NODES * 4);
    int*   rowptr     = (int*)  alloc((size_t)(N_NODES + 1) * 4);
    int*   cursor     = (int*)  alloc((size_t)N_NODES * 4);
    int*   bsum       = (int*)  alloc((size_t)SCAN_BLK * 4);
    float* tbuf       = (float*)alloc((size_t)N_NODES * 4);
    float* rbuf       = (float*)alloc((size_t)N_NODES * 4);
    float* score      = (float*)alloc((size_t)N_NODES * 4);
    int*   start      = (int*)  alloc((size_t)(N_GRAPHS + 1) * 4);

    hipMemsetAsync(counts, 0, (size_t)N_NODES * 4, stream);

    k_gemm   <<<N_NODES / 16, 256, 0, stream>>>(x, Wl, Wr, xlr);
    k_hist   <<<(E_TOT + 255) / 256, 256, 0, stream>>>(ei, counts);
    k_scanA  <<<SCAN_BLK, 256, 0, stream>>>(counts, rowptr, bsum);
    k_scanB  <<<1, 64, 0, stream>>>(bsum, rowptr);
    k_scanC  <<<(N_NODES + 255) / 256, 256, 0, stream>>>(rowptr, bsum, cursor);
    k_scatter<<<(E_TOT + 255) / 256, 256, 0, stream>>>(ei, cursor, sorted_src);
    k_gat    <<<(N_NODES + 3) / 4, 256, 0, stream>>>(xlr, rowptr, sorted_src, att, bias,
                                                     w_rel, w_root, hfeat, tbuf, rbuf);
    k_score  <<<(N_NODES + 255) / 256, 256, 0, stream>>>(rowptr, sorted_src, tbuf, rbuf, b_sc, score);
    k_bounds <<<(N_NODES + 255) / 256, 256, 0, stream>>>(batch, start);
    k_pool   <<<N_GRAPHS, 64, 0, stream>>>(score, hfeat, start, (float*)d_out);
}

// Round 4
// 404.228 us; speedup vs baseline: 10.7777x; 1.1314x over previous
//
#include <hip/hip_runtime.h>
#include <hip/hip_bf16.h>

#define N_NODES 100000
#define N_EDGES 1000000
#define N_GRAPHS 2048
#define F_IN 128
#define NEG_SLOPE 0.2f
#define E_TOT (N_EDGES + N_NODES)       // edges + self-loops
#define SCAN_BLK 98                     // ceil(100000/1024)
#define GEMM_BLOCKS 782                 // ceil(100000/128)
#define HIST_BLOCKS ((E_TOT + 255) / 256)
#define NODE_BLOCKS ((N_NODES + 255) / 256)

// ========== K1: fused  xlr = x @ [W_l|W_r]  +  dst histogram ==================
// GEMM: 128x128 block tile, 256 threads as 16x16, 8x8 register tile.
__global__ __launch_bounds__(256) void k_gemm_hist(const float* __restrict__ x,
                                                   const float* __restrict__ Wl,
                                                   const float* __restrict__ Wr,
                                                   const int* __restrict__ ei,
                                                   float* __restrict__ xlr,
                                                   int* __restrict__ counts) {
    if (blockIdx.x >= GEMM_BLOCKS) {            // -------- histogram part
        int e = (blockIdx.x - GEMM_BLOCKS) * 256 + threadIdx.x;
        if (e < E_TOT) {
            int d = (e < N_EDGES) ? ei[N_EDGES + e] : (e - N_EDGES);
            atomicAdd(&counts[d], 1);
        }
        return;
    }
    __shared__ float xT[8][132];                // [k][row], +4 pad
    __shared__ float wsm[8][132];               // [k][col], +4 pad
    int tid = threadIdx.x;
    int row0 = blockIdx.x * 128;
    int tx = tid & 15, ty = tid >> 4;
    int sr = tid >> 1;                          // x-stage row 0..127
    int sk = (tid & 1) * 4;                     // x-stage k offset
    int wk = tid >> 5;                          // W-stage k 0..7
    int wc = (tid & 31) * 4;                    // W-stage col 0..124
    float acc[8][8];
#pragma unroll
    for (int i = 0; i < 8; ++i)
#pragma unroll
        for (int j = 0; j < 8; ++j) acc[i][j] = 0.f;

    for (int k0 = 0; k0 < F_IN; k0 += 8) {
        int r = row0 + sr;
        float4 xv = (r < N_NODES) ? *(const float4*)(x + (size_t)r * F_IN + k0 + sk)
                                  : make_float4(0.f, 0.f, 0.f, 0.f);
        xT[sk + 0][sr] = xv.x; xT[sk + 1][sr] = xv.y;
        xT[sk + 2][sr] = xv.z; xT[sk + 3][sr] = xv.w;
        float4 wv = (wc < 64) ? *(const float4*)(Wl + (size_t)(k0 + wk) * 64 + wc)
                              : *(const float4*)(Wr + (size_t)(k0 + wk) * 64 + wc - 64);
        *(float4*)&wsm[wk][wc] = wv;
        __syncthreads();
#pragma unroll
        for (int kk = 0; kk < 8; ++kk) {
            float a[8], b[8];
            *(float4*)&a[0] = *(float4*)&xT[kk][ty * 8];
            *(float4*)&a[4] = *(float4*)&xT[kk][ty * 8 + 4];
            *(float4*)&b[0] = *(float4*)&wsm[kk][tx * 8];
            *(float4*)&b[4] = *(float4*)&wsm[kk][tx * 8 + 4];
#pragma unroll
            for (int i = 0; i < 8; ++i)
#pragma unroll
                for (int j = 0; j < 8; ++j) acc[i][j] += a[i] * b[j];
        }
        __syncthreads();
    }
#pragma unroll
    for (int i = 0; i < 8; ++i) {
        int r = row0 + ty * 8 + i;
        if (r < N_NODES) {
            *(float4*)(xlr + (size_t)r * 128 + tx * 8)     = make_float4(acc[i][0], acc[i][1], acc[i][2], acc[i][3]);
            *(float4*)(xlr + (size_t)r * 128 + tx * 8 + 4) = make_float4(acc[i][4], acc[i][5], acc[i][6], acc[i][7]);
        }
    }
}

// ========== K2: block-level exclusive scan of counts -> rowptr + bsum =========
__global__ __launch_bounds__(256) void k_scanA(const int* __restrict__ counts,
                                               int* __restrict__ rowptr,
                                               int* __restrict__ bsum) {
    __shared__ int sh[256];
    int t = threadIdx.x, b = blockIdx.x;
    int base = b * 1024 + t * 4;
    int v[4]; int s = 0;
#pragma unroll
    for (int i = 0; i < 4; ++i) {
        int idx = base + i;
        v[i] = (idx < N_NODES) ? counts[idx] : 0;
        s += v[i];
    }
    sh[t] = s; __syncthreads();
    for (int off = 1; off < 256; off <<= 1) {
        int xv = (t >= off) ? sh[t - off] : 0;
        __syncthreads();
        sh[t] += xv;
        __syncthreads();
    }
    int run = sh[t] - s;
    if (t == 255) bsum[b] = sh[255];
#pragma unroll
    for (int i = 0; i < 4; ++i) {
        int idx = base + i;
        if (idx < N_NODES) rowptr[idx] = run;
        run += v[i];
    }
}

// ========== K3: fused  (bsum prefix + rowptr/cursor finalize)  +  bounds ======
__global__ __launch_bounds__(256) void k_scanC_bounds(int* __restrict__ rowptr,
                                                      const int* __restrict__ bsum,
                                                      int* __restrict__ cursor,
                                                      const int* __restrict__ batch,
                                                      int* __restrict__ start) {
    if (blockIdx.x < NODE_BLOCKS) {
        int i = blockIdx.x * 256 + threadIdx.x;
        int target = blockIdx.x >> 2;           // == i>>10 for whole block
        int lane = threadIdx.x & 63;
        int p = 0;
        if (lane < target)                    p  = bsum[lane];
        if (lane + 64 < target && lane + 64 < SCAN_BLK) p += bsum[lane + 64];
#pragma unroll
        for (int o = 1; o < 64; o <<= 1) p += __shfl_xor(p, o, 64);
        if (i < N_NODES) {
            int v = rowptr[i] + p;
            rowptr[i] = v;
            cursor[i] = v;
        }
        if (blockIdx.x == 0 && threadIdx.x == 0) rowptr[N_NODES] = E_TOT;
    } else {
        int i = (blockIdx.x - NODE_BLOCKS) * 256 + threadIdx.x;
        if (i >= N_NODES) return;
        int bi = batch[i];
        int bp = (i == 0) ? -1 : batch[i - 1];
        for (int g = bp + 1; g <= bi; ++g) start[g] = i;
        if (i == N_NODES - 1)
            for (int g = bi + 1; g <= N_GRAPHS; ++g) start[g] = N_NODES;
    }
}

// ========== K4: scatter edges into dst-sorted order ===========================
__global__ __launch_bounds__(256) void k_scatter(const int* __restrict__ ei,
                                                 int* __restrict__ cursor,
                                                 int* __restrict__ sorted_src) {
    int e = blockIdx.x * 256 + threadIdx.x;
    if (e >= E_TOT) return;
    int s, d;
    if (e < N_EDGES) { s = ei[e]; d = ei[N_EDGES + e]; }
    else             { s = d = e - N_EDGES; }
    int pos = atomicAdd(&cursor[d], 1);
    sorted_src[pos] = s;
}

// ========== K5: fused GATv2 per dst (online softmax, 1-edge lookahead) ========
__global__ __launch_bounds__(256) void k_gat(const float* __restrict__ xlr,
                                             const int* __restrict__ rowptr,
                                             const int* __restrict__ sorted_src,
                                             const float* __restrict__ att,
                                             const float* __restrict__ bias,
                                             const float* __restrict__ w_rel,
                                             const float* __restrict__ w_root,
                                             float* __restrict__ hfeat,
                                             float* __restrict__ tbuf,
                                             float* __restrict__ rbuf) {
    int d = blockIdx.x * 4 + (threadIdx.x >> 6);
    if (d >= N_NODES) return;
    int lane = threadIdx.x & 63;
    float xr_l  = xlr[(size_t)d * 128 + 64 + lane];
    float att_l = att[lane];
    int j0 = rowptr[d], j1 = rowptr[d + 1];     // >=1 (self-loop)
    float xls = xlr[(size_t)sorted_src[j0] * 128 + lane];
    float m = -1e30f, wsum = 0.f, acc = 0.f;
    for (int j = j0; j < j1; ++j) {
        float xcur = xls;
        if (j + 1 < j1)                          // prefetch next edge's feature
            xls = xlr[(size_t)sorted_src[j + 1] * 128 + lane];
        float v = xcur + xr_l;
        v = (v > 0.f) ? v : NEG_SLOPE * v;
        float p = v * att_l;
#pragma unroll
        for (int o = 1; o < 32; o <<= 1) p += __shfl_xor(p, o, 64);  // per-head dot
        if (p > m) {
            float sc = __expf(m - p);
            acc *= sc; wsum *= sc; m = p;
        }
        float w = __expf(p - m);
        wsum += w;
        acc += w * xcur;
    }
    float h = acc / wsum + bias[lane];
    hfeat[(size_t)d * 64 + lane] = h;
    float a = h * w_rel[lane];
    float b = h * w_root[lane];
#pragma unroll
    for (int o = 1; o < 64; o <<= 1) { a += __shfl_xor(a, o, 64); b += __shfl_xor(b, o, 64); }
    if (lane == 0) { tbuf[d] = a; rbuf[d] = b; }
}

// ========== K6: score via sorted CSR (minus self-loop term) ===================
__global__ __launch_bounds__(256) void k_score(const int* __restrict__ rowptr,
                                               const int* __restrict__ sorted_src,
                                               const float* __restrict__ t,
                                               const float* __restrict__ r,
                                               const float* __restrict__ b_score,
                                               float* __restrict__ score) {
    int d = blockIdx.x * 256 + threadIdx.x;
    if (d >= N_NODES) return;
    int j0 = rowptr[d], j1 = rowptr[d + 1];
    float sum = 0.f;
    int s = sorted_src[j0];
    for (int j = j0; j < j1; ++j) {
        int s2 = (j + 1 < j1) ? sorted_src[j + 1] : 0;
        sum += t[s];
        s = s2;
    }
    score[d] = sum - t[d] + r[d] + b_score[0];  // sorted list contains self-loop once
}

// ========== K7: per-graph softmax-pool, out = add*(1+1/cnt), 4 waves/graph ====
__global__ __launch_bounds__(256) void k_pool(const float* __restrict__ score,
                                              const float* __restrict__ h,
                                              const int* __restrict__ start,
                                              float* __restrict__ out) {
    __shared__ float sh[4];
    __shared__ float shacc[4][64];
    int g = blockIdx.x;
    int tid = threadIdx.x, w = tid >> 6, lane = tid & 63;
    int n0 = start[g], n1 = start[g + 1];
    int cnt = n1 - n0;
    if (cnt <= 0) { if (tid < 64) out[(size_t)g * 64 + tid] = 0.f; return; }
    // --- max over scores
    float m = -1e30f;
    for (int i = n0 + tid; i < n1; i += 256) m = fmaxf(m, score[i]);
#pragma unroll
    for (int o = 32; o; o >>= 1) m = fmaxf(m, __shfl_xor(m, o, 64));
    if (lane == 0) sh[w] = m;
    __syncthreads();
    m = fmaxf(fmaxf(sh[0], sh[1]), fmaxf(sh[2], sh[3]));
    // --- sum of exp
    float ssum = 0.f;
    for (int i = n0 + tid; i < n1; i += 256) ssum += __expf(score[i] - m);
#pragma unroll
    for (int o = 32; o; o >>= 1) ssum += __shfl_xor(ssum, o, 64);
    __syncthreads();
    if (lane == 0) sh[w] = ssum;
    __syncthreads();
    ssum = sh[0] + sh[1] + sh[2] + sh[3];
    // --- weighted feature accumulation: wave w takes nodes n0+w, step 4
    float acc = 0.f;
    for (int i = n0 + w; i < n1; i += 4)
        acc += __expf(score[i] - m) * h[(size_t)i * 64 + lane];
    shacc[w][lane] = acc;
    __syncthreads();
    if (w == 0) {
        float tot = shacc[0][lane] + shacc[1][lane] + shacc[2][lane] + shacc[3][lane];
        out[(size_t)g * 64 + lane] = tot * (1.f + 1.f / (float)cnt) / ssum;
    }
}

extern "C" void kernel_launch(void* const* d_in, const int* in_sizes, int n_in,
                              void* d_out, int out_size, void* d_ws, size_t ws_size,
                              hipStream_t stream) {
    const float* x      = (const float*)d_in[0];
    const int*   ei     = (const int*)d_in[1];
    const int*   batch  = (const int*)d_in[2];
    const float* Wl     = (const float*)d_in[3];
    const float* Wr     = (const float*)d_in[4];
    const float* att    = (const float*)d_in[5];
    const float* bias   = (const float*)d_in[6];
    const float* w_rel  = (const float*)d_in[7];
    const float* w_root = (const float*)d_in[8];
    const float* b_sc   = (const float*)d_in[9];

    char* ws = (char*)d_ws;
    size_t off = 0;
    auto alloc = [&](size_t bytes) { void* p = ws + off; off += (bytes + 255) & ~255ull; return p; };
    float* xlr        = (float*)alloc((size_t)N_NODES * 128 * 4);
    float* hfeat      = (float*)alloc((size_t)N_NODES * 64 * 4);
    int*   sorted_src = (int*)  alloc((size_t)E_TOT * 4);
    int*   counts     = (int*)  alloc((size_t)N_NODES * 4);
    int*   rowptr     = (int*)  alloc((size_t)(N_NODES + 1) * 4);
    int*   cursor     = (int*)  alloc((size_t)N_NODES * 4);
    int*   bsum       = (int*)  alloc((size_t)SCAN_BLK * 4);
    float* tbuf       = (float*)alloc((size_t)N_NODES * 4);
    float* rbuf       = (float*)alloc((size_t)N_NODES * 4);
    float* score      = (float*)alloc((size_t)N_NODES * 4);
    int*   start      = (int*)  alloc((size_t)(N_GRAPHS + 1) * 4);

    hipMemsetAsync(counts, 0, (size_t)N_NODES * 4, stream);

    k_gemm_hist   <<<GEMM_BLOCKS + HIST_BLOCKS, 256, 0, stream>>>(x, Wl, Wr, ei, xlr, counts);
    k_scanA       <<<SCAN_BLK, 256, 0, stream>>>(counts, rowptr, bsum);
    k_scanC_bounds<<<NODE_BLOCKS * 2, 256, 0, stream>>>(rowptr, bsum, cursor, batch, start);
    k_scatter     <<<(E_TOT + 255) / 256, 256, 0, stream>>>(ei, cursor, sorted_src);
    k_gat         <<<(N_NODES + 3) / 4, 256, 0, stream>>>(xlr, rowptr, sorted_src, att, bias,
                                                          w_rel, w_root, hfeat, tbuf, rbuf);
    k_score       <<<NODE_BLOCKS, 256, 0, stream>>>(rowptr, sorted_src, tbuf, rbuf, b_sc, score);
    k_pool        <<<N_GRAPHS, 256, 0, stream>>>(score, hfeat, start, (float*)d_out);
}

// Round 5
// 354.747 us; speedup vs baseline: 12.2810x; 1.1395x over previous
//
#include <hip/hip_runtime.h>
#include <hip/hip_bf16.h>

#define N_NODES 100000
#define N_EDGES 1000000
#define N_GRAPHS 2048
#define F_IN 128
#define NEG_SLOPE 0.2f
#define E_TOT (N_EDGES + N_NODES)       // edges + self-loops
#define SCAN_BLK 98                     // ceil(100000/1024)
#define GEMM_BLOCKS 782                 // ceil(100000/128)
#define HIST_BLOCKS ((E_TOT + 255) / 256)
#define NODE_BLOCKS ((N_NODES + 255) / 256)

// ========== K1: fused  xlr = x @ [W_l|W_r]  +  dst histogram ==================
__global__ __launch_bounds__(256) void k_gemm_hist(const float* __restrict__ x,
                                                   const float* __restrict__ Wl,
                                                   const float* __restrict__ Wr,
                                                   const int* __restrict__ ei,
                                                   float* __restrict__ xlr,
                                                   int* __restrict__ counts) {
    if (blockIdx.x >= GEMM_BLOCKS) {            // -------- histogram part
        int e = (blockIdx.x - GEMM_BLOCKS) * 256 + threadIdx.x;
        if (e < E_TOT) {
            int d = (e < N_EDGES) ? ei[N_EDGES + e] : (e - N_EDGES);
            atomicAdd(&counts[d], 1);
        }
        return;
    }
    __shared__ float xT[8][132];                // [k][row], +4 pad
    __shared__ float wsm[8][132];               // [k][col], +4 pad
    int tid = threadIdx.x;
    int row0 = blockIdx.x * 128;
    int tx = tid & 15, ty = tid >> 4;
    int sr = tid >> 1;                          // x-stage row 0..127
    int sk = (tid & 1) * 4;                     // x-stage k offset
    int wk = tid >> 5;                          // W-stage k 0..7
    int wc = (tid & 31) * 4;                    // W-stage col 0..124
    float acc[8][8];
#pragma unroll
    for (int i = 0; i < 8; ++i)
#pragma unroll
        for (int j = 0; j < 8; ++j) acc[i][j] = 0.f;

    for (int k0 = 0; k0 < F_IN; k0 += 8) {
        int r = row0 + sr;
        float4 xv = (r < N_NODES) ? *(const float4*)(x + (size_t)r * F_IN + k0 + sk)
                                  : make_float4(0.f, 0.f, 0.f, 0.f);
        xT[sk + 0][sr] = xv.x; xT[sk + 1][sr] = xv.y;
        xT[sk + 2][sr] = xv.z; xT[sk + 3][sr] = xv.w;
        float4 wv = (wc < 64) ? *(const float4*)(Wl + (size_t)(k0 + wk) * 64 + wc)
                              : *(const float4*)(Wr + (size_t)(k0 + wk) * 64 + wc - 64);
        *(float4*)&wsm[wk][wc] = wv;
        __syncthreads();
#pragma unroll
        for (int kk = 0; kk < 8; ++kk) {
            float a[8], b[8];
            *(float4*)&a[0] = *(float4*)&xT[kk][ty * 8];
            *(float4*)&a[4] = *(float4*)&xT[kk][ty * 8 + 4];
            *(float4*)&b[0] = *(float4*)&wsm[kk][tx * 8];
            *(float4*)&b[4] = *(float4*)&wsm[kk][tx * 8 + 4];
#pragma unroll
            for (int i = 0; i < 8; ++i)
#pragma unroll
                for (int j = 0; j < 8; ++j) acc[i][j] += a[i] * b[j];
        }
        __syncthreads();
    }
#pragma unroll
    for (int i = 0; i < 8; ++i) {
        int r = row0 + ty * 8 + i;
        if (r < N_NODES) {
            *(float4*)(xlr + (size_t)r * 128 + tx * 8)     = make_float4(acc[i][0], acc[i][1], acc[i][2], acc[i][3]);
            *(float4*)(xlr + (size_t)r * 128 + tx * 8 + 4) = make_float4(acc[i][4], acc[i][5], acc[i][6], acc[i][7]);
        }
    }
}

// ========== K2: block-level exclusive scan of counts -> rowptr + bsum =========
__global__ __launch_bounds__(256) void k_scanA(const int* __restrict__ counts,
                                               int* __restrict__ rowptr,
                                               int* __restrict__ bsum) {
    __shared__ int sh[256];
    int t = threadIdx.x, b = blockIdx.x;
    int base = b * 1024 + t * 4;
    int v[4]; int s = 0;
#pragma unroll
    for (int i = 0; i < 4; ++i) {
        int idx = base + i;
        v[i] = (idx < N_NODES) ? counts[idx] : 0;
        s += v[i];
    }
    sh[t] = s; __syncthreads();
    for (int off = 1; off < 256; off <<= 1) {
        int xv = (t >= off) ? sh[t - off] : 0;
        __syncthreads();
        sh[t] += xv;
        __syncthreads();
    }
    int run = sh[t] - s;
    if (t == 255) bsum[b] = sh[255];
#pragma unroll
    for (int i = 0; i < 4; ++i) {
        int idx = base + i;
        if (idx < N_NODES) rowptr[idx] = run;
        run += v[i];
    }
}

// ========== K3: fused  (bsum prefix + rowptr/cursor finalize)  +  bounds ======
__global__ __launch_bounds__(256) void k_scanC_bounds(int* __restrict__ rowptr,
                                                      const int* __restrict__ bsum,
                                                      int* __restrict__ cursor,
                                                      const int* __restrict__ batch,
                                                      int* __restrict__ start) {
    if (blockIdx.x < NODE_BLOCKS) {
        int i = blockIdx.x * 256 + threadIdx.x;
        int target = blockIdx.x >> 2;           // == i>>10 for whole block
        int lane = threadIdx.x & 63;
        int p = 0;
        if (lane < target)                    p  = bsum[lane];
        if (lane + 64 < target && lane + 64 < SCAN_BLK) p += bsum[lane + 64];
#pragma unroll
        for (int o = 1; o < 64; o <<= 1) p += __shfl_xor(p, o, 64);
        if (i < N_NODES) {
            int v = rowptr[i] + p;
            rowptr[i] = v;
            cursor[i] = v;
        }
        if (blockIdx.x == 0 && threadIdx.x == 0) rowptr[N_NODES] = E_TOT;
    } else {
        int i = (blockIdx.x - NODE_BLOCKS) * 256 + threadIdx.x;
        if (i >= N_NODES) return;
        int bi = batch[i];
        int bp = (i == 0) ? -1 : batch[i - 1];
        for (int g = bp + 1; g <= bi; ++g) start[g] = i;
        if (i == N_NODES - 1)
            for (int g = bi + 1; g <= N_GRAPHS; ++g) start[g] = N_NODES;
    }
}

// ========== K4: scatter edges into dst-sorted order ===========================
__global__ __launch_bounds__(256) void k_scatter(const int* __restrict__ ei,
                                                 int* __restrict__ cursor,
                                                 int* __restrict__ sorted_src) {
    int e = blockIdx.x * 256 + threadIdx.x;
    if (e >= E_TOT) return;
    int s, d;
    if (e < N_EDGES) { s = ei[e]; d = ei[N_EDGES + e]; }
    else             { s = d = e - N_EDGES; }
    int pos = atomicAdd(&cursor[d], 1);
    sorted_src[pos] = s;
}

// ========== K5: fused GATv2 per dst — CHUNKED online softmax (8 edges) ========
// 8 independent logit chains per chunk; one state merge per chunk.
__global__ __launch_bounds__(256) void k_gat(const float* __restrict__ xlr,
                                             const int* __restrict__ rowptr,
                                             const int* __restrict__ sorted_src,
                                             const float* __restrict__ att,
                                             const float* __restrict__ bias,
                                             const float* __restrict__ w_rel,
                                             const float* __restrict__ w_root,
                                             float* __restrict__ hfeat,
                                             float* __restrict__ tbuf,
                                             float* __restrict__ rbuf) {
    int d = blockIdx.x * 4 + (threadIdx.x >> 6);
    if (d >= N_NODES) return;
    int lane = threadIdx.x & 63;
    float xr_l  = xlr[(size_t)d * 128 + 64 + lane];
    float att_l = att[lane];
    int j0 = rowptr[d], j1 = rowptr[d + 1];     // >=1 (self-loop)
    float m = -1e30f, wsum = 0.f, acc = 0.f;
    for (int jc = j0; jc < j1; jc += 8) {
        int n = j1 - jc;                        // valid count this chunk (may be >8)
        float p[8], xv[8];
#pragma unroll
        for (int i = 0; i < 8; ++i) {           // 8 independent gathers
            int jj = (i < n) ? (jc + i) : jc;
            int s = sorted_src[jj];
            xv[i] = xlr[(size_t)s * 128 + lane];
        }
#pragma unroll
        for (int i = 0; i < 8; ++i) {
            float v = xv[i] + xr_l;
            v = (v > 0.f) ? v : NEG_SLOPE * v;
            p[i] = v * att_l;
        }
#pragma unroll
        for (int o = 1; o <= 16; o <<= 1)       // per-head (32-lane) sums, 8-way ILP
#pragma unroll
            for (int i = 0; i < 8; ++i)
                p[i] += __shfl_xor(p[i], o, 64);
#pragma unroll
        for (int i = 0; i < 8; ++i)
            if (i >= n) p[i] = -1e30f;          // mask tail -> w = 0
        float mc = p[0];
#pragma unroll
        for (int i = 1; i < 8; ++i) mc = fmaxf(mc, p[i]);
        float cws = 0.f, cacc = 0.f;
#pragma unroll
        for (int i = 0; i < 8; ++i) {
            float w = __expf(p[i] - mc);        // 8 independent exps
            cws += w;
            cacc += w * xv[i];
        }
        float mnew = fmaxf(m, mc);              // single merge per chunk
        float fo = __expf(m - mnew), fn = __expf(mc - mnew);
        wsum = wsum * fo + cws * fn;
        acc  = acc  * fo + cacc * fn;
        m = mnew;
    }
    float h = acc / wsum + bias[lane];
    hfeat[(size_t)d * 64 + lane] = h;
    float a = h * w_rel[lane];
    float b = h * w_root[lane];
#pragma unroll
    for (int o = 1; o < 64; o <<= 1) { a += __shfl_xor(a, o, 64); b += __shfl_xor(b, o, 64); }
    if (lane == 0) { tbuf[d] = a; rbuf[d] = b; }
}

// ========== K6: fused score + per-graph softmax-pool (block per graph) ========
__global__ __launch_bounds__(256) void k_pool(const int* __restrict__ rowptr,
                                              const int* __restrict__ sorted_src,
                                              const float* __restrict__ t,
                                              const float* __restrict__ r,
                                              const float* __restrict__ b_score,
                                              float* __restrict__ score,
                                              const float* __restrict__ h,
                                              const int* __restrict__ start,
                                              float* __restrict__ out) {
    __shared__ float sh[4];
    __shared__ float shacc[4][64];
    int g = blockIdx.x;
    int tid = threadIdx.x, w = tid >> 6, lane = tid & 63;
    int n0 = start[g], n1 = start[g + 1];
    int cnt = n1 - n0;
    if (cnt <= 0) { if (tid < 64) out[(size_t)g * 64 + tid] = 0.f; return; }
    float bsc = b_score[0];
    // --- phase 1: scores for this graph's nodes (GraphConv aggr via sorted CSR)
    for (int i = n0 + tid; i < n1; i += 256) {
        int jj0 = rowptr[i], jj1 = rowptr[i + 1];
        float sum = 0.f;
        int s = sorted_src[jj0];
        for (int j = jj0; j < jj1; ++j) {
            int s2 = (j + 1 < jj1) ? sorted_src[j + 1] : 0;
            sum += t[s];
            s = s2;
        }
        score[i] = sum - t[i] + r[i] + bsc;     // self-loop in list once -> subtract
    }
    __syncthreads();
    // --- phase 2: softmax over scores + weighted pool
    float m = -1e30f;
    for (int i = n0 + tid; i < n1; i += 256) m = fmaxf(m, score[i]);
#pragma unroll
    for (int o = 32; o; o >>= 1) m = fmaxf(m, __shfl_xor(m, o, 64));
    if (lane == 0) sh[w] = m;
    __syncthreads();
    m = fmaxf(fmaxf(sh[0], sh[1]), fmaxf(sh[2], sh[3]));
    float ssum = 0.f;
    for (int i = n0 + tid; i < n1; i += 256) ssum += __expf(score[i] - m);
#pragma unroll
    for (int o = 32; o; o >>= 1) ssum += __shfl_xor(ssum, o, 64);
    __syncthreads();
    if (lane == 0) sh[w] = ssum;
    __syncthreads();
    ssum = sh[0] + sh[1] + sh[2] + sh[3];
    float acc = 0.f;
    for (int i = n0 + w; i < n1; i += 4)
        acc += __expf(score[i] - m) * h[(size_t)i * 64 + lane];
    shacc[w][lane] = acc;
    __syncthreads();
    if (w == 0) {
        float tot = shacc[0][lane] + shacc[1][lane] + shacc[2][lane] + shacc[3][lane];
        out[(size_t)g * 64 + lane] = tot * (1.f + 1.f / (float)cnt) / ssum;
    }
}

extern "C" void kernel_launch(void* const* d_in, const int* in_sizes, int n_in,
                              void* d_out, int out_size, void* d_ws, size_t ws_size,
                              hipStream_t stream) {
    const float* x      = (const float*)d_in[0];
    const int*   ei     = (const int*)d_in[1];
    const int*   batch  = (const int*)d_in[2];
    const float* Wl     = (const float*)d_in[3];
    const float* Wr     = (const float*)d_in[4];
    const float* att    = (const float*)d_in[5];
    const float* bias   = (const float*)d_in[6];
    const float* w_rel  = (const float*)d_in[7];
    const float* w_root = (const float*)d_in[8];
    const float* b_sc   = (const float*)d_in[9];

    char* ws = (char*)d_ws;
    size_t off = 0;
    auto alloc = [&](size_t bytes) { void* p = ws + off; off += (bytes + 255) & ~255ull; return p; };
    float* xlr        = (float*)alloc((size_t)N_NODES * 128 * 4);
    float* hfeat      = (float*)alloc((size_t)N_NODES * 64 * 4);
    int*   sorted_src = (int*)  alloc((size_t)E_TOT * 4);
    int*   counts     = (int*)  alloc((size_t)N_NODES * 4);
    int*   rowptr     = (int*)  alloc((size_t)(N_NODES + 1) * 4);
    int*   cursor     = (int*)  alloc((size_t)N_NODES * 4);
    int*   bsum       = (int*)  alloc((size_t)SCAN_BLK * 4);
    float* tbuf       = (float*)alloc((size_t)N_NODES * 4);
    float* rbuf       = (float*)alloc((size_t)N_NODES * 4);
    float* score      = (float*)alloc((size_t)N_NODES * 4);
    int*   start      = (int*)  alloc((size_t)(N_GRAPHS + 1) * 4);

    hipMemsetAsync(counts, 0, (size_t)N_NODES * 4, stream);

    k_gemm_hist   <<<GEMM_BLOCKS + HIST_BLOCKS, 256, 0, stream>>>(x, Wl, Wr, ei, xlr, counts);
    k_scanA       <<<SCAN_BLK, 256, 0, stream>>>(counts, rowptr, bsum);
    k_scanC_bounds<<<NODE_BLOCKS * 2, 256, 0, stream>>>(rowptr, bsum, cursor, batch, start);
    k_scatter     <<<(E_TOT + 255) / 256, 256, 0, stream>>>(ei, cursor, sorted_src);
    k_gat         <<<(N_NODES + 3) / 4, 256, 0, stream>>>(xlr, rowptr, sorted_src, att, bias,
                                                          w_rel, w_root, hfeat, tbuf, rbuf);
    k_pool        <<<N_GRAPHS, 256, 0, stream>>>(rowptr, sorted_src, tbuf, rbuf, b_sc,
                                                 score, hfeat, start, (float*)d_out);
}

// Round 7
// 265.285 us; speedup vs baseline: 16.4225x; 1.3372x over previous
//
#include <hip/hip_runtime.h>
#include <hip/hip_bf16.h>

#define N_NODES 100000
#define N_EDGES 1000000
#define N_GRAPHS 2048
#define F_IN 128
#define NEG_SLOPE 0.2f
#define E_TOT (N_EDGES + N_NODES)       // edges + self-loops
#define SCAN_BLK 98                     // ceil(100000/1024)
#define GEMM_BLOCKS 782                 // ceil(100000/128)
#define HIST_BLOCKS ((E_TOT + 255) / 256)
#define NODE_BLOCKS ((N_NODES + 255) / 256)

// ---- DPP helpers: ctrl must be a compile-time constant -> template param ----
template <int CTRL>
__device__ __forceinline__ float dpp_add(float x) {
    return x + __int_as_float(__builtin_amdgcn_update_dpp(
        0, __float_as_int(x), CTRL, 0xf, 0xf, true));
}
// sum over each 32-lane half, result broadcast to all lanes of that half
__device__ __forceinline__ float head_sum_bcast(float x) {
    x = dpp_add<0x111>(x);   // row_shr:1
    x = dpp_add<0x112>(x);   // row_shr:2
    x = dpp_add<0x114>(x);   // row_shr:4
    x = dpp_add<0x118>(x);   // row_shr:8  -> lane15 of each row = row sum
    x = dpp_add<0x142>(x);   // row_bcast:15 -> lane31/63 = 32-half sum
    // broadcast lane31 within each 32-group: BitMode and=0,or=31,xor=0 -> 0x03E0
    return __int_as_float(__builtin_amdgcn_ds_swizzle(__float_as_int(x), 0x03E0));
}
// full 64-lane sum, valid in lane 63 only
__device__ __forceinline__ float full_sum64(float x) {
    x = dpp_add<0x111>(x);
    x = dpp_add<0x112>(x);
    x = dpp_add<0x114>(x);
    x = dpp_add<0x118>(x);
    x = dpp_add<0x142>(x);   // row_bcast:15
    x = dpp_add<0x143>(x);   // row_bcast:31
    return x;
}

// ========== K1: fused  xlr = x @ [W_l|W_r]  +  dst histogram (+rank) ==========
__global__ __launch_bounds__(256) void k_gemm_hist(const float* __restrict__ x,
                                                   const float* __restrict__ Wl,
                                                   const float* __restrict__ Wr,
                                                   const int* __restrict__ ei,
                                                   float* __restrict__ xlr,
                                                   int* __restrict__ counts,
                                                   int* __restrict__ rank_) {
    if (blockIdx.x >= GEMM_BLOCKS) {            // -------- histogram part
        int e = (blockIdx.x - GEMM_BLOCKS) * 256 + threadIdx.x;
        if (e < E_TOT) {
            int d = (e < N_EDGES) ? ei[N_EDGES + e] : (e - N_EDGES);
            rank_[e] = atomicAdd(&counts[d], 1);    // rank within dst
        }
        return;
    }
    __shared__ float xT[8][132];                // [k][row], +4 pad
    __shared__ float wsm[8][132];               // [k][col], +4 pad
    int tid = threadIdx.x;
    int row0 = blockIdx.x * 128;
    int tx = tid & 15, ty = tid >> 4;
    int sr = tid >> 1;
    int sk = (tid & 1) * 4;
    int wk = tid >> 5;
    int wc = (tid & 31) * 4;
    float acc[8][8];
#pragma unroll
    for (int i = 0; i < 8; ++i)
#pragma unroll
        for (int j = 0; j < 8; ++j) acc[i][j] = 0.f;

    for (int k0 = 0; k0 < F_IN; k0 += 8) {
        int r = row0 + sr;
        float4 xv = (r < N_NODES) ? *(const float4*)(x + (size_t)r * F_IN + k0 + sk)
                                  : make_float4(0.f, 0.f, 0.f, 0.f);
        xT[sk + 0][sr] = xv.x; xT[sk + 1][sr] = xv.y;
        xT[sk + 2][sr] = xv.z; xT[sk + 3][sr] = xv.w;
        float4 wv = (wc < 64) ? *(const float4*)(Wl + (size_t)(k0 + wk) * 64 + wc)
                              : *(const float4*)(Wr + (size_t)(k0 + wk) * 64 + wc - 64);
        *(float4*)&wsm[wk][wc] = wv;
        __syncthreads();
#pragma unroll
        for (int kk = 0; kk < 8; ++kk) {
            float a[8], b[8];
            *(float4*)&a[0] = *(float4*)&xT[kk][ty * 8];
            *(float4*)&a[4] = *(float4*)&xT[kk][ty * 8 + 4];
            *(float4*)&b[0] = *(float4*)&wsm[kk][tx * 8];
            *(float4*)&b[4] = *(float4*)&wsm[kk][tx * 8 + 4];
#pragma unroll
            for (int i = 0; i < 8; ++i)
#pragma unroll
                for (int j = 0; j < 8; ++j) acc[i][j] += a[i] * b[j];
        }
        __syncthreads();
    }
#pragma unroll
    for (int i = 0; i < 8; ++i) {
        int r = row0 + ty * 8 + i;
        if (r < N_NODES) {
            *(float4*)(xlr + (size_t)r * 128 + tx * 8)     = make_float4(acc[i][0], acc[i][1], acc[i][2], acc[i][3]);
            *(float4*)(xlr + (size_t)r * 128 + tx * 8 + 4) = make_float4(acc[i][4], acc[i][5], acc[i][6], acc[i][7]);
        }
    }
}

// ========== K2: block-level exclusive scan of counts -> rowptr + bsum =========
__global__ __launch_bounds__(256) void k_scanA(const int* __restrict__ counts,
                                               int* __restrict__ rowptr,
                                               int* __restrict__ bsum) {
    __shared__ int sh[256];
    int t = threadIdx.x, b = blockIdx.x;
    int base = b * 1024 + t * 4;
    int v[4]; int s = 0;
#pragma unroll
    for (int i = 0; i < 4; ++i) {
        int idx = base + i;
        v[i] = (idx < N_NODES) ? counts[idx] : 0;
        s += v[i];
    }
    sh[t] = s; __syncthreads();
    for (int off = 1; off < 256; off <<= 1) {
        int xv = (t >= off) ? sh[t - off] : 0;
        __syncthreads();
        sh[t] += xv;
        __syncthreads();
    }
    int run = sh[t] - s;
    if (t == 255) bsum[b] = sh[255];
#pragma unroll
    for (int i = 0; i < 4; ++i) {
        int idx = base + i;
        if (idx < N_NODES) rowptr[idx] = run;
        run += v[i];
    }
}

// ========== K3: fused  (bsum prefix + rowptr finalize)  +  bounds =============
__global__ __launch_bounds__(256) void k_scanC_bounds(int* __restrict__ rowptr,
                                                      const int* __restrict__ bsum,
                                                      const int* __restrict__ batch,
                                                      int* __restrict__ start) {
    if (blockIdx.x < NODE_BLOCKS) {
        int i = blockIdx.x * 256 + threadIdx.x;
        int target = blockIdx.x >> 2;           // == i>>10 for whole block
        int lane = threadIdx.x & 63;
        int p = 0;
        if (lane < target)                    p  = bsum[lane];
        if (lane + 64 < target && lane + 64 < SCAN_BLK) p += bsum[lane + 64];
#pragma unroll
        for (int o = 1; o < 64; o <<= 1) p += __shfl_xor(p, o, 64);
        if (i < N_NODES) rowptr[i] += p;
        if (blockIdx.x == 0 && threadIdx.x == 0) rowptr[N_NODES] = E_TOT;
    } else {
        int i = (blockIdx.x - NODE_BLOCKS) * 256 + threadIdx.x;
        if (i >= N_NODES) return;
        int bi = batch[i];
        int bp = (i == 0) ? -1 : batch[i - 1];
        for (int g = bp + 1; g <= bi; ++g) start[g] = i;
        if (i == N_NODES - 1)
            for (int g = bi + 1; g <= N_GRAPHS; ++g) start[g] = N_NODES;
    }
}

// ========== K4: atomic-free scatter via precomputed rank ======================
__global__ __launch_bounds__(256) void k_scatter(const int* __restrict__ ei,
                                                 const int* __restrict__ rowptr,
                                                 const int* __restrict__ rank_,
                                                 int* __restrict__ sorted_src) {
    int e = blockIdx.x * 256 + threadIdx.x;
    if (e >= E_TOT) return;
    int s, d;
    if (e < N_EDGES) { s = ei[e]; d = ei[N_EDGES + e]; }
    else             { s = d = e - N_EDGES; }
    sorted_src[rowptr[d] + rank_[e]] = s;
}

// ========== K5: fused GATv2 per dst — scalarized CSR + DPP reductions =========
__global__ __launch_bounds__(256) void k_gat(const float* __restrict__ xlr,
                                             const int* __restrict__ rowptr,
                                             const int* __restrict__ sorted_src,
                                             const float* __restrict__ att,
                                             const float* __restrict__ bias,
                                             const float* __restrict__ w_rel,
                                             const float* __restrict__ w_root,
                                             float* __restrict__ hfeat,
                                             float* __restrict__ tbuf,
                                             float* __restrict__ rbuf) {
    int lane = threadIdx.x & 63;
    int du = __builtin_amdgcn_readfirstlane(blockIdx.x * 4 + (threadIdx.x >> 6));
    if (du >= N_NODES) return;                  // wave-uniform exit
    float xr_l  = xlr[(size_t)du * 128 + 64 + lane];
    float att_l = att[lane];
    int j0 = __builtin_amdgcn_readfirstlane(rowptr[du]);
    int j1 = __builtin_amdgcn_readfirstlane(rowptr[du + 1]);   // >= j0+1 (self-loop)
    float m = -1e30f, wsum = 0.f, acc = 0.f;
    for (int jc = j0; jc < j1; jc += 8) {
        int n = j1 - jc;                        // valid edges this chunk (may exceed 8)
        int jj = jc + (lane & 7);
        if (jj > j1 - 1) jj = j1 - 1;
        int sv = sorted_src[jj];                // edge i's src sits in lane i (i<8)
        float p[8], xv[8];
#pragma unroll
        for (int i = 0; i < 8; ++i) {           // SGPR-based gathers
            int s = __builtin_amdgcn_readlane(sv, i);
            const float* ps = xlr + (size_t)(unsigned)s * 128;
            xv[i] = ps[lane];
        }
#pragma unroll
        for (int i = 0; i < 8; ++i) {
            float v = xv[i] + xr_l;
            v = (v > 0.f) ? v : NEG_SLOPE * v;
            p[i] = v * att_l;
        }
#pragma unroll
        for (int i = 0; i < 8; ++i)             // per-head 32-lane dot, DPP
            p[i] = head_sum_bcast(p[i]);
#pragma unroll
        for (int i = 0; i < 8; ++i)
            if (i >= n) p[i] = -1e30f;          // mask tail -> w = 0
        float mc = p[0];
#pragma unroll
        for (int i = 1; i < 8; ++i) mc = fmaxf(mc, p[i]);
        float cws = 0.f, cacc = 0.f;
#pragma unroll
        for (int i = 0; i < 8; ++i) {
            float w = __expf(p[i] - mc);
            cws += w;
            cacc += w * xv[i];
        }
        float mnew = fmaxf(m, mc);
        float fo = __expf(m - mnew), fn = __expf(mc - mnew);
        wsum = wsum * fo + cws * fn;
        acc  = acc  * fo + cacc * fn;
        m = mnew;
    }
    float h = acc / wsum + bias[lane];
    hfeat[(size_t)du * 64 + lane] = h;
    float a = full_sum64(h * w_rel[lane]);
    float b = full_sum64(h * w_root[lane]);
    if (lane == 63) { tbuf[du] = a; rbuf[du] = b; }
}

// ========== K6: fused score + per-graph softmax-pool (block per graph) ========
__global__ __launch_bounds__(256) void k_pool(const int* __restrict__ rowptr,
                                              const int* __restrict__ sorted_src,
                                              const float* __restrict__ t,
                                              const float* __restrict__ r,
                                              const float* __restrict__ b_score,
                                              float* __restrict__ score,
                                              const float* __restrict__ h,
                                              const int* __restrict__ start,
                                              float* __restrict__ out) {
    __shared__ float sh[4];
    __shared__ float shacc[4][64];
    int g = blockIdx.x;
    int tid = threadIdx.x, w = tid >> 6, lane = tid & 63;
    int n0 = start[g], n1 = start[g + 1];
    int cnt = n1 - n0;
    if (cnt <= 0) { if (tid < 64) out[(size_t)g * 64 + tid] = 0.f; return; }
    float bsc = b_score[0];
    // --- phase 1: scores (GraphConv aggr via sorted CSR), 4-way ILP
    for (int i = n0 + tid; i < n1; i += 256) {
        int jj0 = rowptr[i], jj1 = rowptr[i + 1];
        float sum = 0.f;
        int j = jj0;
        for (; j + 4 <= jj1; j += 4) {
            int s0 = sorted_src[j], s1 = sorted_src[j + 1];
            int s2 = sorted_src[j + 2], s3 = sorted_src[j + 3];
            sum += t[s0] + t[s1] + t[s2] + t[s3];
        }
        for (; j < jj1; ++j) sum += t[sorted_src[j]];
        score[i] = sum - t[i] + r[i] + bsc;     // self-loop in list once -> subtract
    }
    __syncthreads();
    // --- phase 2: softmax over scores + weighted pool
    float m = -1e30f;
    for (int i = n0 + tid; i < n1; i += 256) m = fmaxf(m, score[i]);
#pragma unroll
    for (int o = 32; o; o >>= 1) m = fmaxf(m, __shfl_xor(m, o, 64));
    if (lane == 0) sh[w] = m;
    __syncthreads();
    m = fmaxf(fmaxf(sh[0], sh[1]), fmaxf(sh[2], sh[3]));
    float ssum = 0.f;
    for (int i = n0 + tid; i < n1; i += 256) ssum += __expf(score[i] - m);
#pragma unroll
    for (int o = 32; o; o >>= 1) ssum += __shfl_xor(ssum, o, 64);
    __syncthreads();
    if (lane == 0) sh[w] = ssum;
    __syncthreads();
    ssum = sh[0] + sh[1] + sh[2] + sh[3];
    float acc = 0.f;
    for (int i = n0 + w; i < n1; i += 4)
        acc += __expf(score[i] - m) * h[(size_t)i * 64 + lane];
    shacc[w][lane] = acc;
    __syncthreads();
    if (w == 0) {
        float tot = shacc[0][lane] + shacc[1][lane] + shacc[2][lane] + shacc[3][lane];
        out[(size_t)g * 64 + lane] = tot * (1.f + 1.f / (float)cnt) / ssum;
    }
}

extern "C" void kernel_launch(void* const* d_in, const int* in_sizes, int n_in,
                              void* d_out, int out_size, void* d_ws, size_t ws_size,
                              hipStream_t stream) {
    const float* x      = (const float*)d_in[0];
    const int*   ei     = (const int*)d_in[1];
    const int*   batch  = (const int*)d_in[2];
    const float* Wl     = (const float*)d_in[3];
    const float* Wr     = (const float*)d_in[4];
    const float* att    = (const float*)d_in[5];
    const float* bias   = (const float*)d_in[6];
    const float* w_rel  = (const float*)d_in[7];
    const float* w_root = (const float*)d_in[8];
    const float* b_sc   = (const float*)d_in[9];

    char* ws = (char*)d_ws;
    size_t off = 0;
    auto alloc = [&](size_t bytes) { void* p = ws + off; off += (bytes + 255) & ~255ull; return p; };
    float* xlr        = (float*)alloc((size_t)N_NODES * 128 * 4);
    float* hfeat      = (float*)alloc((size_t)N_NODES * 64 * 4);
    int*   sorted_src = (int*)  alloc((size_t)E_TOT * 4);
    int*   rank_      = (int*)  alloc((size_t)E_TOT * 4);
    int*   counts     = (int*)  alloc((size_t)N_NODES * 4);
    int*   rowptr     = (int*)  alloc((size_t)(N_NODES + 1) * 4);
    int*   bsum       = (int*)  alloc((size_t)SCAN_BLK * 4);
    float* tbuf       = (float*)alloc((size_t)N_NODES * 4);
    float* rbuf       = (float*)alloc((size_t)N_NODES * 4);
    float* score      = (float*)alloc((size_t)N_NODES * 4);
    int*   start      = (int*)  alloc((size_t)(N_GRAPHS + 1) * 4);

    (void)hipMemsetAsync(counts, 0, (size_t)N_NODES * 4, stream);

    k_gemm_hist   <<<GEMM_BLOCKS + HIST_BLOCKS, 256, 0, stream>>>(x, Wl, Wr, ei, xlr, counts, rank_);
    k_scanA       <<<SCAN_BLK, 256, 0, stream>>>(counts, rowptr, bsum);
    k_scanC_bounds<<<NODE_BLOCKS * 2, 256, 0, stream>>>(rowptr, bsum, batch, start);
    k_scatter     <<<(E_TOT + 255) / 256, 256, 0, stream>>>(ei, rowptr, rank_, sorted_src);
    k_gat         <<<(N_NODES + 3) / 4, 256, 0, stream>>>(xlr, rowptr, sorted_src, att, bias,
                                                          w_rel, w_root, hfeat, tbuf, rbuf);
    k_pool        <<<N_GRAPHS, 256, 0, stream>>>(rowptr, sorted_src, tbuf, rbuf, b_sc,
                                                 score, hfeat, start, (float*)d_out);
}